// Round 7
// baseline (717.531 us; speedup 1.0000x reference)
//
#include <hip/hip_runtime.h>
#include <hip/hip_bf16.h>
#include <math.h>

typedef __bf16 bf16;
typedef __attribute__((ext_vector_type(4))) __bf16 bf16x4;
typedef __attribute__((ext_vector_type(8))) __bf16 bf16x8;
typedef __attribute__((ext_vector_type(4))) float f32x4;

#define N_NODES 20000
#define N_EDGES 320000
#define E2 (N_EDGES + N_NODES)   // 340000 edges incl self-loops
#define F_IN 50
#define D1 1024                  // H1*C1
#define NP12 2048                // padded GEMM out-cols, layer 2 ([W|Wl])
#define NP3 896                  // padded GEMM out-cols, layer 3 (726+121=847 -> 896)
#define SG 2048                  // row stride of GEMM output buffer
#define KA 320                   // layer-1 fused K: 4*64 aggx + 64 x

// params pool element offsets (bf16 pool)
#define PO_A1S 0
#define PO_A1D 1024
#define PO_B1  2048
#define PO_BL1 3072
#define PO_A2S 4096
#define PO_A2D 5120
#define PO_B2  6144
#define PO_BL2 7168
#define PO_A3S 8192
#define PO_A3D 8918
#define PO_B3  9644
#define PO_BL3 9765
#define PO_END 9886

__device__ __forceinline__ int clampi(int v, int lo, int hi)
{
    return v < lo ? lo : (v > hi ? hi : v);
}

__device__ __forceinline__ float loadf(const void* p, long idx, int isb)
{
    return isb ? (float)((const bf16*)p)[idx] : ((const float*)p)[idx];
}

__device__ __forceinline__ int loadei(const int* ei, long idx, int i64)
{
    return i64 ? ei[2 * idx] : ei[idx];
}

// --------------------------------------------------------------- detect -----
__global__ void k_detect(const int* __restrict__ ei,
                         const unsigned short* __restrict__ xw,
                         int* __restrict__ flags)
{
    if (blockIdx.x != 0 || threadIdx.x != 0) return;
    int allz = 1;
    for (int i = 0; i < 128; ++i)
        if (ei[2 * i + 1] != 0) { allz = 0; break; }
    int inr = 0;
    for (int i = 0; i < 128; ++i) {
        int e = (xw[2 * i] >> 7) & 0xFF;
        if (e >= 100 && e <= 140) inr++;
    }
    flags[0] = allz;
    flags[1] = (inr >= 64) ? 1 : 0;
}

// ---------------------------------------------------------------- GEMM ------
// m97-style 128x128 tile, BK=64, global_load_lds width-16, XCD swizzle,
// XOR k-chunk LDS swizzle (bank-conflict-free). Optional fused bias+ELU.
__global__ __launch_bounds__(256) void k_gemm(const bf16* __restrict__ A,
                                              const bf16* __restrict__ Bt,
                                              bf16* __restrict__ C,
                                              int M, int K, int lda, int ldb, int ldc,
                                              int mtiles, int ntiles,
                                              const bf16* __restrict__ bias, int act)
{
    __shared__ bf16 As[128 * 64];
    __shared__ bf16 Bs[128 * 64];

    int id = blockIdx.x;
    int gfull = mtiles >> 3;
    int base  = gfull * 8 * ntiles;
    int x, y;
    if (id < base) {
        int gsz = 8 * ntiles;
        int g = id / gsz;
        int r = id - g * gsz;
        x = g * 8 + (r & 7);
        y = r >> 3;
    } else {
        int rem = mtiles - (gfull << 3);
        int r = id - base;
        x = (gfull << 3) + r % rem;
        y = r / rem;
    }
    const int m0 = x * 128;
    const int n0 = y * 128;

    const int tid  = threadIdx.x;
    const int wave = tid >> 6;
    const int lane = tid & 63;
    const int wm   = (wave >> 1) * 64;
    const int wn   = (wave & 1) * 64;
    const int frow  = lane & 15;

    const int srow = wave * 32 + (lane >> 3);
    const int scol = (((lane & 7) ^ (lane >> 3)) * 8);

    f32x4 acc[4][4];
#pragma unroll
    for (int i = 0; i < 4; ++i)
#pragma unroll
        for (int j = 0; j < 4; ++j)
#pragma unroll
            for (int r = 0; r < 4; ++r) acc[i][j][r] = 0.f;

    for (int k0 = 0; k0 < K; k0 += 64) {
#pragma unroll
        for (int i = 0; i < 4; ++i) {
            int ra = srow + i * 8;
            int ga = m0 + ra; if (ga > M - 1) ga = M - 1;   // junk rows -> discarded C rows
            __builtin_amdgcn_global_load_lds(
                (const __attribute__((address_space(1))) void*)(A + (size_t)ga * lda + k0 + scol),
                (__attribute__((address_space(3))) void*)(As + wave * 2048 + i * 512),
                16, 0, 0);
            int gb = n0 + ra;
            __builtin_amdgcn_global_load_lds(
                (const __attribute__((address_space(1))) void*)(Bt + (size_t)gb * ldb + k0 + scol),
                (__attribute__((address_space(3))) void*)(Bs + wave * 2048 + i * 512),
                16, 0, 0);
        }
        __syncthreads();
#pragma unroll
        for (int kk = 0; kk < 2; ++kk) {
            const int coff = (((kk * 4 + (lane >> 4)) ^ (frow & 7)) << 3);
            bf16x8 af[4], bfr[4];
#pragma unroll
            for (int i = 0; i < 4; ++i) {
                af[i]  = *(const bf16x8*)(As + (wm + i * 16 + frow) * 64 + coff);
                bfr[i] = *(const bf16x8*)(Bs + (wn + i * 16 + frow) * 64 + coff);
            }
#pragma unroll
            for (int i = 0; i < 4; ++i)
#pragma unroll
                for (int j = 0; j < 4; ++j)
                    acc[i][j] = __builtin_amdgcn_mfma_f32_16x16x32_bf16(af[i], bfr[j], acc[i][j], 0, 0, 0);
        }
        __syncthreads();
    }

#pragma unroll
    for (int i = 0; i < 4; ++i) {
#pragma unroll
        for (int j = 0; j < 4; ++j) {
            int rbase = m0 + wm + i * 16 + (lane >> 4) * 4;
            int col   = n0 + wn + j * 16 + frow;
            float bv = bias ? (float)bias[col] : 0.f;
#pragma unroll
            for (int r = 0; r < 4; ++r) {
                int row = rbase + r;
                if (row < M) {
                    float v = acc[i][j][r] + bv;
                    if (act) v = (v > 0.f) ? v : (expf(v) - 1.f);
                    C[(size_t)row * ldc + col] = (bf16)v;
                }
            }
        }
    }
}

// ------------------------------------------------------------ prep kernels --
// x -> A2[n*KA + 256 + k] (padded to 64)
__global__ void k_padx(const void* __restrict__ x, bf16* __restrict__ A2,
                       const int* __restrict__ flags)
{
    int idx = blockIdx.x * 256 + threadIdx.x;
    if (idx >= N_NODES * 64) return;
    int isb = flags[1];
    int n = idx >> 6, k = idx & 63;
    A2[(size_t)n * KA + 256 + k] = (k < F_IN) ? (bf16)loadf(x, (long)n * F_IN + k, isb)
                                              : (bf16)0.f;
}

// ws[k][h] = sum_c W1[k, h*256+c]*a1s[h,c]; wd likewise; bsum = b1+bl1
__global__ __launch_bounds__(256) void k_veca(const void* __restrict__ W1,
                                              const void* __restrict__ a1s,
                                              const void* __restrict__ a1d,
                                              const void* __restrict__ b1,
                                              const void* __restrict__ bl1,
                                              float* __restrict__ ws, float* __restrict__ wd,
                                              bf16* __restrict__ bsum,
                                              const int* __restrict__ flags)
{
    const int isb = flags[1];
    const int t = threadIdx.x;
    const int k = t >> 2, h = t & 3;
    float s = 0.f, d = 0.f;
    if (k < F_IN) {
        for (int c = 0; c < 256; ++c) {
            float wv = loadf(W1, (long)k * D1 + h * 256 + c, isb);
            s += wv * loadf(a1s, h * 256 + c, isb);
            d += wv * loadf(a1d, h * 256 + c, isb);
        }
    }
    ws[k * 4 + h] = s;
    wd[k * 4 + h] = d;
    for (int j = t; j < D1; j += 256)
        bsum[j] = (bf16)(loadf(b1, j, isb) + loadf(bl1, j, isb));
}

// fused layer-1 B^T [1024 x KA]: k'<256 blockdiag(W1), k'>=256 Wl1
__global__ void k_wfuse1(const void* __restrict__ W1, const void* __restrict__ Wl1,
                         bf16* __restrict__ Bt, const int* __restrict__ flags)
{
    int idx = blockIdx.x * 256 + threadIdx.x;
    if (idx >= D1 * KA) return;
    int isb = flags[1];
    int j = idx / KA;
    int kp = idx - j * KA;
    float v = 0.f;
    if (kp < 256) {
        int hp = kp >> 6, k = kp & 63;
        if ((j >> 8) == hp && k < F_IN) v = loadf(W1, (long)k * D1 + j, isb);
    } else {
        int k = kp - 256;
        if (k < F_IN) v = loadf(Wl1, (long)k * D1 + j, isb);
    }
    Bt[idx] = (bf16)v;
}

// Tiled transpose-concat: Bt[n][k] = [Wa | Wb | 0](k, n), K=1024 rows.
__global__ __launch_bounds__(256) void k_wcatT(const void* __restrict__ Wa,
                                               const void* __restrict__ Wb,
                                               bf16* __restrict__ Bt,
                                               int split, int da, int db,
                                               const int* __restrict__ flags)
{
    __shared__ bf16 T[64][65];
    const int isb = flags[1];
    const int k0 = blockIdx.x * 64;
    const int n0 = blockIdx.y * 64;
    const int r = threadIdx.x >> 6;    // 0..3
    const int c = threadIdx.x & 63;
    const int n = n0 + c;
#pragma unroll
    for (int kk = 0; kk < 16; ++kk) {
        int k = k0 + r + kk * 4;
        float v = 0.f;
        if (n < split)           v = loadf(Wa, (long)k * da + n, isb);
        else if (n < split + db) v = loadf(Wb, (long)k * db + (n - split), isb);
        T[r + kk * 4][c] = (bf16)v;
    }
    __syncthreads();
#pragma unroll
    for (int kk = 0; kk < 16; ++kk) {
        int nn = r + kk * 4;
        Bt[(size_t)(n0 + nn) * 1024 + k0 + c] = T[c][nn];
    }
}

struct P12 { const void* s[12]; };

__global__ void k_params(P12 ps, bf16* __restrict__ pool, const int* __restrict__ flags)
{
    const int off[13] = {PO_A1S, PO_A1D, PO_B1, PO_BL1, PO_A2S, PO_A2D, PO_B2,
                         PO_BL2, PO_A3S, PO_A3D, PO_B3, PO_BL3, PO_END};
    int idx = blockIdx.x * 256 + threadIdx.x;
    if (idx >= PO_END) return;
    int isb = flags[1];
    int seg = 0;
    while (idx >= off[seg + 1]) seg++;
    pool[idx] = (bf16)loadf(ps.s[seg], idx - off[seg], isb);
}

// ------------------------------------------------------------- CSR build ----
__global__ void k_count(const int* __restrict__ ei, int* __restrict__ cnt,
                        const int* __restrict__ flags)
{
    int e = blockIdx.x * 256 + threadIdx.x;
    if (e >= E2) return;
    int i64 = flags[0];
    int d = (e < N_EDGES) ? loadei(ei, (long)N_EDGES + e, i64) : (e - N_EDGES);
    d = clampi(d, 0, N_NODES - 1);
    atomicAdd(&cnt[d], 1);
}

__global__ __launch_bounds__(256) void k_scan(const int* __restrict__ cnt, int* __restrict__ rp)
{
    __shared__ int ssum[256];
    int tid = threadIdx.x;
    const int chunk = (N_NODES + 255) / 256;
    int lo = tid * chunk;
    int hi = lo + chunk; if (hi > N_NODES) hi = N_NODES;
    int s = 0;
    for (int i = lo; i < hi; ++i) s += cnt[i];
    ssum[tid] = s;
    __syncthreads();
    if (tid == 0) {
        int run = 0;
        for (int i = 0; i < 256; ++i) { int t = ssum[i]; ssum[i] = run; run += t; }
        rp[N_NODES] = run;
    }
    __syncthreads();
    int run = ssum[tid];
    for (int i = lo; i < hi; ++i) { rp[i] = run; run += cnt[i]; }
}

__global__ void k_copy(const int* __restrict__ rp, int* __restrict__ cur)
{
    int i = blockIdx.x * 256 + threadIdx.x;
    if (i < N_NODES) cur[i] = rp[i];
}

__global__ void k_fill(const int* __restrict__ ei, int* __restrict__ cur,
                       int* __restrict__ ss, const int* __restrict__ flags)
{
    int e = blockIdx.x * 256 + threadIdx.x;
    if (e >= E2) return;
    int i64 = flags[0];
    int s, d;
    if (e < N_EDGES) {
        s = loadei(ei, e, i64);
        d = loadei(ei, (long)N_EDGES + e, i64);
    } else {
        s = e - N_EDGES; d = s;
    }
    s = clampi(s, 0, N_NODES - 1);
    d = clampi(d, 0, N_NODES - 1);
    int pos = atomicAdd(&cur[d], 1);
    if (pos >= 0 && pos < E2) ss[pos] = s;
}

// ----------------------------------------------------- attention kernels ----
// layer-1 logits: es[n,h] = sum_k x[n,k]*ws[k,h] (wave per node)
__global__ __launch_bounds__(256) void k_logits1(const bf16* __restrict__ A2,
                                                 const float* __restrict__ ws,
                                                 const float* __restrict__ wd,
                                                 float* __restrict__ es, float* __restrict__ ed)
{
    const int wave = threadIdx.x >> 6;
    const int lane = threadIdx.x & 63;
    const int n = blockIdx.x * 4 + wave;
    if (n >= N_NODES) return;
    float xv = (float)A2[(size_t)n * KA + 256 + lane];
    f32x4 wsv = *(const f32x4*)(ws + lane * 4);
    f32x4 wdv = *(const f32x4*)(wd + lane * 4);
    float s[4], d[4];
#pragma unroll
    for (int h = 0; h < 4; ++h) { s[h] = xv * wsv[h]; d[h] = xv * wdv[h]; }
#pragma unroll
    for (int off = 32; off; off >>= 1)
#pragma unroll
        for (int h = 0; h < 4; ++h) {
            s[h] += __shfl_xor(s[h], off);
            d[h] += __shfl_xor(d[h], off);
        }
    if (lane == 0) {
#pragma unroll
        for (int h = 0; h < 4; ++h) { es[n * 4 + h] = s[h]; ed[n * 4 + h] = d[h]; }
    }
}

// layer-1 aggregate: aggx[n,h,k] = sum_e alpha[e,h] x[src_e,k] (block per node)
__global__ __launch_bounds__(256) void k_aggx(bf16* __restrict__ A2,
                                              const float* __restrict__ es,
                                              const float* __restrict__ ed,
                                              const int* __restrict__ rp,
                                              const int* __restrict__ ss)
{
    __shared__ float smx[4], sinv[4];
    __shared__ float sal[64 * 4];
    __shared__ int   ssrc[64];

    const int n   = blockIdx.x;
    const int tid = threadIdx.x;
    int r0 = clampi(rp[n], 0, E2);
    int r1 = clampi(rp[n + 1], r0, E2);
    const int deg = r1 - r0;

    // phase 1: per-head max + denom (subwarps 0..3 active)
    const int sw = tid >> 5, ln = tid & 31;
    if (sw < 4) {
        int h = sw;
        float edn = ed[n * 4 + h];
        float mx = -1e30f;
        for (int e = ln; e < deg; e += 32) {
            int s = clampi(ss[r0 + e], 0, N_NODES - 1);
            float w = es[s * 4 + h] + edn;
            w = (w > 0.f) ? w : 0.2f * w;
            mx = fmaxf(mx, w);
        }
#pragma unroll
        for (int off = 16; off; off >>= 1) mx = fmaxf(mx, __shfl_xor(mx, off, 32));
        float sm = 0.f;
        for (int e = ln; e < deg; e += 32) {
            int s = clampi(ss[r0 + e], 0, N_NODES - 1);
            float w = es[s * 4 + h] + edn;
            w = (w > 0.f) ? w : 0.2f * w;
            sm += expf(w - mx);
        }
#pragma unroll
        for (int off = 16; off; off >>= 1) sm += __shfl_xor(sm, off, 32);
        if (ln == 0) { smx[h] = mx; sinv[h] = 1.f / fmaxf(sm, 1e-16f); }
    }
    __syncthreads();

    const int k  = tid & 63;
    const int hh = tid >> 6;
    float acc = 0.f;

    for (int e0 = 0; e0 < deg; e0 += 64) {
        int ce = min(64, deg - e0);
        __syncthreads();
        if (tid < ce * 4) {
            int e = tid >> 2, h = tid & 3;
            int s = clampi(ss[r0 + e0 + e], 0, N_NODES - 1);
            float w = es[s * 4 + h] + ed[n * 4 + h];
            w = (w > 0.f) ? w : 0.2f * w;
            sal[e * 4 + h] = expf(w - smx[h]) * sinv[h];
            if (h == 0) ssrc[e] = s;
        }
        __syncthreads();
        for (int e = 0; e < ce; ++e) {
            int s = ssrc[e];
            float xv = (float)A2[(size_t)s * KA + 256 + k];
            acc += sal[e * 4 + hh] * xv;
        }
    }
    A2[(size_t)n * KA + hh * 64 + k] = (bf16)acc;
}

// layers 2/3 logits on h (wave per node)
template <int H, int C>
__global__ __launch_bounds__(256) void k_logits(const bf16* __restrict__ G,
                                                const bf16* __restrict__ as_,
                                                const bf16* __restrict__ ad_,
                                                float* __restrict__ es, float* __restrict__ ed)
{
    const int wave = threadIdx.x >> 6;
    const int lane = threadIdx.x & 63;
    const int n = blockIdx.x * 4 + wave;
    if (n >= N_NODES) return;

#pragma unroll
    for (int h = 0; h < H; ++h) {
        float s = 0.f, d = 0.f;
        if constexpr (C == 256) {
            bf16x4 g  = *(const bf16x4*)(G + (size_t)n * SG + h * 256 + lane * 4);
            bf16x4 av = *(const bf16x4*)(as_ + h * 256 + lane * 4);
            bf16x4 dv = *(const bf16x4*)(ad_ + h * 256 + lane * 4);
#pragma unroll
            for (int j = 0; j < 4; ++j) {
                float gv = (float)g[j];
                s += gv * (float)av[j];
                d += gv * (float)dv[j];
            }
        } else {
            for (int c = lane; c < C; c += 64) {
                float hv = (float)G[(size_t)n * SG + h * C + c];
                s += hv * (float)as_[h * C + c];
                d += hv * (float)ad_[h * C + c];
            }
        }
#pragma unroll
        for (int off = 32; off; off >>= 1) {
            s += __shfl_xor(s, off);
            d += __shfl_xor(d, off);
        }
        if (lane == 0) { es[n * H + h] = s; ed[n * H + h] = d; }
    }
}

// Fused per-dst-node softmax + gather-aggregate + bias + skip (+mean/ELU).
template <int H, int C, bool MEAN, bool ELU, bool EXTOUT>
__global__ __launch_bounds__(256) void k_agg(const bf16* __restrict__ G,
                                             const bf16* __restrict__ S,
                                             const float* __restrict__ es,
                                             const float* __restrict__ ed,
                                             const int* __restrict__ rp,
                                             const int* __restrict__ ss,
                                             const bf16* __restrict__ bgat,
                                             const bf16* __restrict__ bskip,
                                             void* __restrict__ out, int sout,
                                             const int* __restrict__ flags)
{
    constexpr int D  = H * C;
    constexpr int NV = (D + 3) / 4;
    constexpr int CH = 64;
    __shared__ float smx[H], sinv[H];
    __shared__ float sal[CH * H];
    __shared__ int   ssrc[CH];

    const int n   = blockIdx.x;
    const int tid = threadIdx.x;
    int r0 = clampi(rp[n], 0, E2);
    int r1 = clampi(rp[n + 1], r0, E2);
    const int deg = r1 - r0;

    const int sw = tid >> 5, ln = tid & 31;
    for (int h = sw; h < H; h += 8) {
        float edn = ed[n * H + h];
        float mx = -1e30f;
        for (int e = ln; e < deg; e += 32) {
            int s = clampi(ss[r0 + e], 0, N_NODES - 1);
            float w = es[s * H + h] + edn;
            w = (w > 0.f) ? w : 0.2f * w;
            mx = fmaxf(mx, w);
        }
#pragma unroll
        for (int off = 16; off; off >>= 1) mx = fmaxf(mx, __shfl_xor(mx, off, 32));
        float sm = 0.f;
        for (int e = ln; e < deg; e += 32) {
            int s = clampi(ss[r0 + e], 0, N_NODES - 1);
            float w = es[s * H + h] + edn;
            w = (w > 0.f) ? w : 0.2f * w;
            sm += expf(w - mx);
        }
#pragma unroll
        for (int off = 16; off; off >>= 1) sm += __shfl_xor(sm, off, 32);
        if (ln == 0) { smx[h] = mx; sinv[h] = 1.f / fmaxf(sm, 1e-16f); }
    }
    __syncthreads();

    const int c0 = tid * 4;
    int hj[4];
#pragma unroll
    for (int j = 0; j < 4; ++j) {
        int c = c0 + j;
        hj[j] = (c < D) ? (c / C) : 0;
    }
    const bool active = (tid < NV);

    float acc[4] = {0.f, 0.f, 0.f, 0.f};

    for (int e0 = 0; e0 < deg; e0 += CH) {
        int ce = min(CH, deg - e0);
        __syncthreads();
        for (int t = tid; t < ce * H; t += 256) {
            int e = t / H, h = t - e * H;
            int s = clampi(ss[r0 + e0 + e], 0, N_NODES - 1);
            float w = es[s * H + h] + ed[n * H + h];
            w = (w > 0.f) ? w : 0.2f * w;
            sal[e * H + h] = expf(w - smx[h]) * sinv[h];
            if (h == 0) ssrc[e] = s;
        }
        __syncthreads();
        if (active) {
            for (int e = 0; e < ce; ++e) {
                int s = ssrc[e];
                bf16x4 g = *(const bf16x4*)(G + (size_t)s * SG + c0);
                const float* al = sal + e * H;
#pragma unroll
                for (int j = 0; j < 4; ++j)
                    acc[j] += al[hj[j]] * (float)g[j];
            }
        }
    }

    const int outbf = EXTOUT ? flags[1] : 1;

    if constexpr (!MEAN) {
        if (active) {
            bf16x4 bg = *(const bf16x4*)(bgat + c0);
            bf16x4 sk = *(const bf16x4*)(S + (size_t)n * SG + c0);
            bf16x4 bs = *(const bf16x4*)(bskip + c0);
            bf16x4 ov;
#pragma unroll
            for (int j = 0; j < 4; ++j) {
                float v = acc[j] + (float)bg[j] + (float)sk[j] + (float)bs[j];
                if (ELU) v = (v > 0.f) ? v : (expf(v) - 1.f);
                ov[j] = (bf16)v;
            }
            *(bf16x4*)((bf16*)out + (size_t)n * sout + c0) = ov;
        }
    } else {
        __shared__ float sagg[D];
        if (active) {
#pragma unroll
            for (int j = 0; j < 4; ++j) {
                int c = c0 + j;
                if (c < D) sagg[c] = acc[j];
            }
        }
        __syncthreads();
        for (int c = tid; c < C; c += 256) {
            float v = 0.f;
#pragma unroll
            for (int h = 0; h < H; ++h) v += sagg[h * C + c];
            v *= (1.f / H);
            v += (float)bgat[c] + (float)S[(size_t)n * SG + c] + (float)bskip[c];
            if (outbf) ((bf16*)out)[(size_t)n * sout + c] = (bf16)v;
            else       ((float*)out)[(size_t)n * sout + c] = v;
        }
    }
}

// ----------------------------------------------------------------- launch ---
extern "C" void kernel_launch(void* const* d_in, const int* in_sizes, int n_in,
                              void* d_out, int out_size, void* d_ws, size_t ws_size,
                              hipStream_t stream)
{
    const void* x   = d_in[0];
    const int*  ei  = (const int*)d_in[1];
    const void* W1  = d_in[2];
    const void* Wl1 = d_in[6];
    const void* W2  = d_in[8];
    const void* Wl2 = d_in[12];
    const void* W3  = d_in[14];
    const void* Wl3 = d_in[18];

    P12 ps;
    ps.s[0] = d_in[3];  ps.s[1] = d_in[4];  ps.s[2] = d_in[5];  ps.s[3] = d_in[7];
    ps.s[4] = d_in[9];  ps.s[5] = d_in[10]; ps.s[6] = d_in[11]; ps.s[7] = d_in[13];
    ps.s[8] = d_in[15]; ps.s[9] = d_in[16]; ps.s[10] = d_in[17]; ps.s[11] = d_in[19];

    char* w = (char*)d_ws;
    auto alloc = [&](size_t bytes) {
        char* p = w;
        w += (bytes + 255) & ~(size_t)255;
        return p;
    };
    int*   flags = (int*)alloc(64);
    int*   cnt   = (int*)alloc((size_t)N_NODES * 4);
    int*   rp    = (int*)alloc((size_t)(N_NODES + 1) * 4);
    int*   cur   = (int*)alloc((size_t)N_NODES * 4);
    int*   ss    = (int*)alloc((size_t)E2 * 4);
    float* es    = (float*)alloc((size_t)N_NODES * 6 * 4);
    float* ed    = (float*)alloc((size_t)N_NODES * 6 * 4);
    bf16*  pool  = (bf16*)alloc((size_t)PO_END * 2);
    float* ws1   = (float*)alloc((size_t)64 * 4 * 4);
    float* wd1   = (float*)alloc((size_t)64 * 4 * 4);
    bf16*  bsum  = (bf16*)alloc((size_t)D1 * 2);
    bf16*  Bt    = (bf16*)alloc((size_t)NP12 * 1024 * 2);
    bf16*  X     = (bf16*)alloc((size_t)N_NODES * D1 * 2);   // x1/x2
    bf16*  WS    = (bf16*)alloc((size_t)N_NODES * SG * 2);   // GEMM out [gat|skip]
    bf16*  A2    = WS;   // layer-1 A'' [N x KA] aliases WS (dead during layer 1)

    k_detect<<<1, 64, 0, stream>>>(ei, (const unsigned short*)x, flags);

    hipMemsetAsync(cnt, 0, N_NODES * 4, stream);
    k_count<<<(E2 + 255) / 256, 256, 0, stream>>>(ei, cnt, flags);
    k_scan<<<1, 256, 0, stream>>>(cnt, rp);
    k_copy<<<(N_NODES + 255) / 256, 256, 0, stream>>>(rp, cur);
    k_fill<<<(E2 + 255) / 256, 256, 0, stream>>>(ei, cur, ss, flags);

    k_params<<<(PO_END + 255) / 256, 256, 0, stream>>>(ps, pool, flags);

    const dim3 blk(256);
    const int MT = (N_NODES + 127) / 128;   // 157

    // ---- layer 1 (restructured): aggregate x, then fused GEMM K=320
    k_veca<<<1, 256, 0, stream>>>(W1, ps.s[0], ps.s[1], ps.s[2], ps.s[3],
                                  ws1, wd1, bsum, flags);
    k_padx<<<(N_NODES * 64 + 255) / 256, 256, 0, stream>>>(x, A2, flags);
    k_wfuse1<<<(D1 * KA + 255) / 256, 256, 0, stream>>>(W1, Wl1, Bt, flags);
    k_logits1<<<N_NODES / 4, 256, 0, stream>>>(A2, ws1, wd1, es, ed);
    k_aggx<<<N_NODES, 256, 0, stream>>>(A2, es, ed, rp, ss);
    k_gemm<<<MT * (D1 / 128), blk, 0, stream>>>(A2, Bt, X, N_NODES, KA, KA, KA, D1,
                                                MT, D1 / 128, bsum, 1);   // x1 = ELU(...)

    // ---- layer 2: K=1024, out 2048 = [GAT 1024 | skip 1024]
    k_wcatT<<<dim3(16, NP12 / 64), blk, 0, stream>>>(W2, Wl2, Bt, 1024, 1024, 1024, flags);
    k_gemm<<<MT * (NP12 / 128), blk, 0, stream>>>(X, Bt, WS, N_NODES, 1024, 1024, 1024, SG,
                                                  MT, NP12 / 128, (const bf16*)nullptr, 0);
    k_logits<4, 256><<<N_NODES / 4, 256, 0, stream>>>(WS, pool + PO_A2S, pool + PO_A2D, es, ed);
    k_agg<4, 256, false, true, false><<<N_NODES, 256, 0, stream>>>(
        WS, WS + D1, es, ed, rp, ss, pool + PO_B2, pool + PO_BL2, X, D1, flags);

    // ---- layer 3: K=1024, out 896 = [GAT 726 | skip 121 | pad]
    k_wcatT<<<dim3(16, NP3 / 64), blk, 0, stream>>>(W3, Wl3, Bt, 726, 726, 121, flags);
    k_gemm<<<MT * (NP3 / 128), blk, 0, stream>>>(X, Bt, WS, N_NODES, 1024, 1024, 1024, SG,
                                                 MT, NP3 / 128, (const bf16*)nullptr, 0);
    k_logits<6, 121><<<N_NODES / 4, 256, 0, stream>>>(WS, pool + PO_A3S, pool + PO_A3D, es, ed);
    k_agg<6, 121, true, false, true><<<N_NODES, 256, 0, stream>>>(
        WS, WS + 726, es, ed, rp, ss, pool + PO_B3, pool + PO_BL3, d_out, 121, flags);
}

// Round 8
// 662.029 us; speedup vs baseline: 1.0838x; 1.0838x over previous
//
#include <hip/hip_runtime.h>
#include <hip/hip_bf16.h>
#include <math.h>

typedef __bf16 bf16;
typedef __attribute__((ext_vector_type(4))) __bf16 bf16x4;
typedef __attribute__((ext_vector_type(8))) __bf16 bf16x8;
typedef __attribute__((ext_vector_type(4))) float f32x4;

#define N_NODES 20000
#define N_EDGES 320000
#define E2 (N_EDGES + N_NODES)   // 340000 edges incl self-loops
#define F_IN 50
#define D1 1024                  // H1*C1
#define NP12 2048                // padded GEMM out-cols, layer 2 ([W|Wl])
#define NP3 896                  // padded GEMM out-cols, layer 3 (726+121=847 -> 896)
#define SG 2048                  // row stride of GEMM output buffer
#define KA 320                   // layer-1 fused K: 4*64 aggx + 64 x

// params pool element offsets (bf16 pool)
#define PO_A1S 0
#define PO_A1D 1024
#define PO_B1  2048
#define PO_BL1 3072
#define PO_A2S 4096
#define PO_A2D 5120
#define PO_B2  6144
#define PO_BL2 7168
#define PO_A3S 8192
#define PO_A3D 8918
#define PO_B3  9644
#define PO_BL3 9765
#define PO_END 9886

__device__ __forceinline__ int clampi(int v, int lo, int hi)
{
    return v < lo ? lo : (v > hi ? hi : v);
}

__device__ __forceinline__ float loadf(const void* p, long idx, int isb)
{
    return isb ? (float)((const bf16*)p)[idx] : ((const float*)p)[idx];
}

__device__ __forceinline__ int loadei(const int* ei, long idx, int i64)
{
    return i64 ? ei[2 * idx] : ei[idx];
}

// --------------------------------------------------------------- detect -----
__global__ void k_detect(const int* __restrict__ ei,
                         const unsigned short* __restrict__ xw,
                         int* __restrict__ flags)
{
    if (blockIdx.x != 0 || threadIdx.x != 0) return;
    int allz = 1;
    for (int i = 0; i < 128; ++i)
        if (ei[2 * i + 1] != 0) { allz = 0; break; }
    int inr = 0;
    for (int i = 0; i < 128; ++i) {
        int e = (xw[2 * i] >> 7) & 0xFF;
        if (e >= 100 && e <= 140) inr++;
    }
    flags[0] = allz;
    flags[1] = (inr >= 64) ? 1 : 0;
}

// ---------------------------------------------------------------- GEMM ------
// m97-style 128x128 tile, BK=64, global_load_lds width-16, XCD swizzle,
// XOR k-chunk LDS swizzle. BACT (compile-time): fused bias+ELU epilogue.
template <bool BACT>
__global__ __launch_bounds__(256) void k_gemm(const bf16* __restrict__ A,
                                              const bf16* __restrict__ Bt,
                                              bf16* __restrict__ C,
                                              int M, int K, int lda, int ldb, int ldc,
                                              int mtiles, int ntiles,
                                              const bf16* __restrict__ bias)
{
    __shared__ bf16 As[128 * 64];
    __shared__ bf16 Bs[128 * 64];

    int id = blockIdx.x;
    int gfull = mtiles >> 3;
    int base  = gfull * 8 * ntiles;
    int x, y;
    if (id < base) {
        int gsz = 8 * ntiles;
        int g = id / gsz;
        int r = id - g * gsz;
        x = g * 8 + (r & 7);
        y = r >> 3;
    } else {
        int rem = mtiles - (gfull << 3);
        int r = id - base;
        x = (gfull << 3) + r % rem;
        y = r / rem;
    }
    const int m0 = x * 128;
    const int n0 = y * 128;

    const int tid  = threadIdx.x;
    const int wave = tid >> 6;
    const int lane = tid & 63;
    const int wm   = (wave >> 1) * 64;
    const int wn   = (wave & 1) * 64;
    const int frow  = lane & 15;

    const int srow = wave * 32 + (lane >> 3);
    const int scol = (((lane & 7) ^ (lane >> 3)) * 8);

    f32x4 acc[4][4];
#pragma unroll
    for (int i = 0; i < 4; ++i)
#pragma unroll
        for (int j = 0; j < 4; ++j)
#pragma unroll
            for (int r = 0; r < 4; ++r) acc[i][j][r] = 0.f;

    for (int k0 = 0; k0 < K; k0 += 64) {
#pragma unroll
        for (int i = 0; i < 4; ++i) {
            int ra = srow + i * 8;
            int ga = m0 + ra; if (ga > M - 1) ga = M - 1;   // junk rows -> discarded C rows
            __builtin_amdgcn_global_load_lds(
                (const __attribute__((address_space(1))) void*)(A + (size_t)ga * lda + k0 + scol),
                (__attribute__((address_space(3))) void*)(As + wave * 2048 + i * 512),
                16, 0, 0);
            int gb = n0 + ra;
            __builtin_amdgcn_global_load_lds(
                (const __attribute__((address_space(1))) void*)(Bt + (size_t)gb * ldb + k0 + scol),
                (__attribute__((address_space(3))) void*)(Bs + wave * 2048 + i * 512),
                16, 0, 0);
        }
        __syncthreads();
#pragma unroll
        for (int kk = 0; kk < 2; ++kk) {
            const int coff = (((kk * 4 + (lane >> 4)) ^ (frow & 7)) << 3);
            bf16x8 af[4], bfr[4];
#pragma unroll
            for (int i = 0; i < 4; ++i) {
                af[i]  = *(const bf16x8*)(As + (wm + i * 16 + frow) * 64 + coff);
                bfr[i] = *(const bf16x8*)(Bs + (wn + i * 16 + frow) * 64 + coff);
            }
#pragma unroll
            for (int i = 0; i < 4; ++i)
#pragma unroll
                for (int j = 0; j < 4; ++j)
                    acc[i][j] = __builtin_amdgcn_mfma_f32_16x16x32_bf16(af[i], bfr[j], acc[i][j], 0, 0, 0);
        }
        __syncthreads();
    }

#pragma unroll
    for (int i = 0; i < 4; ++i) {
#pragma unroll
        for (int j = 0; j < 4; ++j) {
            int rbase = m0 + wm + i * 16 + (lane >> 4) * 4;
            int col   = n0 + wn + j * 16 + frow;
            if constexpr (BACT) {
                float bv = (float)bias[col];
#pragma unroll
                for (int r = 0; r < 4; ++r) {
                    int row = rbase + r;
                    if (row < M) {
                        float v = acc[i][j][r] + bv;
                        v = (v > 0.f) ? v : (expf(v) - 1.f);
                        C[(size_t)row * ldc + col] = (bf16)v;
                    }
                }
            } else {
#pragma unroll
                for (int r = 0; r < 4; ++r) {
                    int row = rbase + r;
                    if (row < M) C[(size_t)row * ldc + col] = (bf16)acc[i][j][r];
                }
            }
        }
    }
}

// ------------------------------------------------------------ prep kernels --
// x -> A2[n*KA + 256 + k] (padded to 64)
__global__ void k_padx(const void* __restrict__ x, bf16* __restrict__ A2,
                       const int* __restrict__ flags)
{
    int idx = blockIdx.x * 256 + threadIdx.x;
    if (idx >= N_NODES * 64) return;
    int isb = flags[1];
    int n = idx >> 6, k = idx & 63;
    A2[(size_t)n * KA + 256 + k] = (k < F_IN) ? (bf16)loadf(x, (long)n * F_IN + k, isb)
                                              : (bf16)0.f;
}

// ws[k][h] = sum_c W1[k, h*256+c]*a1s[h,c]; wd likewise; bsum = b1+bl1.
// grid 64 blocks (one per k); head h = wave, 64-lane wave reduction.
__global__ __launch_bounds__(256) void k_veca(const void* __restrict__ W1,
                                              const void* __restrict__ a1s,
                                              const void* __restrict__ a1d,
                                              const void* __restrict__ b1,
                                              const void* __restrict__ bl1,
                                              float* __restrict__ ws, float* __restrict__ wd,
                                              bf16* __restrict__ bsum,
                                              const int* __restrict__ flags)
{
    const int isb = flags[1];
    const int k = blockIdx.x;          // 0..63
    const int h = threadIdx.x >> 6;
    const int c0 = threadIdx.x & 63;
    float s = 0.f, d = 0.f;
    if (k < F_IN) {
        for (int c = c0; c < 256; c += 64) {
            float wv = loadf(W1, (long)k * D1 + h * 256 + c, isb);
            s += wv * loadf(a1s, h * 256 + c, isb);
            d += wv * loadf(a1d, h * 256 + c, isb);
        }
    }
#pragma unroll
    for (int off = 32; off; off >>= 1) {
        s += __shfl_xor(s, off);
        d += __shfl_xor(d, off);
    }
    if (c0 == 0) { ws[k * 4 + h] = s; wd[k * 4 + h] = d; }
    if (k < 4) {
        int j = k * 256 + threadIdx.x;
        bsum[j] = (bf16)(loadf(b1, j, isb) + loadf(bl1, j, isb));
    }
}

// fused layer-1 B^T [1024 x KA]: k'<256 blockdiag(W1), k'>=256 Wl1
__global__ void k_wfuse1(const void* __restrict__ W1, const void* __restrict__ Wl1,
                         bf16* __restrict__ Bt, const int* __restrict__ flags)
{
    int idx = blockIdx.x * 256 + threadIdx.x;
    if (idx >= D1 * KA) return;
    int isb = flags[1];
    int j = idx / KA;
    int kp = idx - j * KA;
    float v = 0.f;
    if (kp < 256) {
        int hp = kp >> 6, k = kp & 63;
        if ((j >> 8) == hp && k < F_IN) v = loadf(W1, (long)k * D1 + j, isb);
    } else {
        int k = kp - 256;
        if (k < F_IN) v = loadf(Wl1, (long)k * D1 + j, isb);
    }
    Bt[idx] = (bf16)v;
}

// Tiled transpose-concat: Bt[n][k] = [Wa | Wb | 0](k, n), K=1024 rows.
__global__ __launch_bounds__(256) void k_wcatT(const void* __restrict__ Wa,
                                               const void* __restrict__ Wb,
                                               bf16* __restrict__ Bt,
                                               int split, int da, int db,
                                               const int* __restrict__ flags)
{
    __shared__ bf16 T[64][65];
    const int isb = flags[1];
    const int k0 = blockIdx.x * 64;
    const int n0 = blockIdx.y * 64;
    const int r = threadIdx.x >> 6;    // 0..3
    const int c = threadIdx.x & 63;
    const int n = n0 + c;
#pragma unroll
    for (int kk = 0; kk < 16; ++kk) {
        int k = k0 + r + kk * 4;
        float v = 0.f;
        if (n < split)           v = loadf(Wa, (long)k * da + n, isb);
        else if (n < split + db) v = loadf(Wb, (long)k * db + (n - split), isb);
        T[r + kk * 4][c] = (bf16)v;
    }
    __syncthreads();
#pragma unroll
    for (int kk = 0; kk < 16; ++kk) {
        int nn = r + kk * 4;
        Bt[(size_t)(n0 + nn) * 1024 + k0 + c] = T[c][nn];
    }
}

struct P12 { const void* s[12]; };

__global__ void k_params(P12 ps, bf16* __restrict__ pool, const int* __restrict__ flags)
{
    const int off[13] = {PO_A1S, PO_A1D, PO_B1, PO_BL1, PO_A2S, PO_A2D, PO_B2,
                         PO_BL2, PO_A3S, PO_A3D, PO_B3, PO_BL3, PO_END};
    int idx = blockIdx.x * 256 + threadIdx.x;
    if (idx >= PO_END) return;
    int isb = flags[1];
    int seg = 0;
    while (idx >= off[seg + 1]) seg++;
    pool[idx] = (bf16)loadf(ps.s[seg], idx - off[seg], isb);
}

// ------------------------------------------------------------- CSR build ----
__global__ void k_count(const int* __restrict__ ei, int* __restrict__ cnt,
                        const int* __restrict__ flags)
{
    int e = blockIdx.x * 256 + threadIdx.x;
    if (e >= E2) return;
    int i64 = flags[0];
    int d = (e < N_EDGES) ? loadei(ei, (long)N_EDGES + e, i64) : (e - N_EDGES);
    d = clampi(d, 0, N_NODES - 1);
    atomicAdd(&cnt[d], 1);
}

__global__ __launch_bounds__(256) void k_scan(const int* __restrict__ cnt, int* __restrict__ rp)
{
    __shared__ int ssum[256];
    int tid = threadIdx.x;
    const int chunk = (N_NODES + 255) / 256;
    int lo = tid * chunk;
    int hi = lo + chunk; if (hi > N_NODES) hi = N_NODES;
    int s = 0;
    for (int i = lo; i < hi; ++i) s += cnt[i];
    ssum[tid] = s;
    __syncthreads();
    if (tid == 0) {
        int run = 0;
        for (int i = 0; i < 256; ++i) { int t = ssum[i]; ssum[i] = run; run += t; }
        rp[N_NODES] = run;
    }
    __syncthreads();
    int run = ssum[tid];
    for (int i = lo; i < hi; ++i) { rp[i] = run; run += cnt[i]; }
}

__global__ void k_copy(const int* __restrict__ rp, int* __restrict__ cur)
{
    int i = blockIdx.x * 256 + threadIdx.x;
    if (i < N_NODES) cur[i] = rp[i];
}

__global__ void k_fill(const int* __restrict__ ei, int* __restrict__ cur,
                       int* __restrict__ ss, const int* __restrict__ flags)
{
    int e = blockIdx.x * 256 + threadIdx.x;
    if (e >= E2) return;
    int i64 = flags[0];
    int s, d;
    if (e < N_EDGES) {
        s = loadei(ei, e, i64);
        d = loadei(ei, (long)N_EDGES + e, i64);
    } else {
        s = e - N_EDGES; d = s;
    }
    s = clampi(s, 0, N_NODES - 1);
    d = clampi(d, 0, N_NODES - 1);
    int pos = atomicAdd(&cur[d], 1);
    if (pos >= 0 && pos < E2) ss[pos] = s;
}

// ----------------------------------------------------- attention kernels ----
// layer-1 logits: es[n,h] = sum_k x[n,k]*ws[k,h] (wave per node)
__global__ __launch_bounds__(256) void k_logits1(const bf16* __restrict__ A2,
                                                 const float* __restrict__ ws,
                                                 const float* __restrict__ wd,
                                                 float* __restrict__ es, float* __restrict__ ed)
{
    const int wave = threadIdx.x >> 6;
    const int lane = threadIdx.x & 63;
    const int n = blockIdx.x * 4 + wave;
    if (n >= N_NODES) return;
    float xv = (float)A2[(size_t)n * KA + 256 + lane];
    f32x4 wsv = *(const f32x4*)(ws + lane * 4);
    f32x4 wdv = *(const f32x4*)(wd + lane * 4);
    float s[4], d[4];
#pragma unroll
    for (int h = 0; h < 4; ++h) { s[h] = xv * wsv[h]; d[h] = xv * wdv[h]; }
#pragma unroll
    for (int off = 32; off; off >>= 1)
#pragma unroll
        for (int h = 0; h < 4; ++h) {
            s[h] += __shfl_xor(s[h], off);
            d[h] += __shfl_xor(d[h], off);
        }
    if (lane == 0) {
#pragma unroll
        for (int h = 0; h < 4; ++h) { es[n * 4 + h] = s[h]; ed[n * 4 + h] = d[h]; }
    }
}

// layer-1 aggregate: aggx[n,h,k] = sum_e alpha[e,h] x[src_e,k] (block per node)
__global__ __launch_bounds__(256) void k_aggx(bf16* __restrict__ A2,
                                              const float* __restrict__ es,
                                              const float* __restrict__ ed,
                                              const int* __restrict__ rp,
                                              const int* __restrict__ ss)
{
    __shared__ float smx[4], sinv[4], sed[4];
    __shared__ float sal[64 * 4];
    __shared__ int   ssrc[64];

    const int n   = blockIdx.x;
    const int tid = threadIdx.x;
    int r0 = clampi(rp[n], 0, E2);
    int r1 = clampi(rp[n + 1], r0, E2);
    const int deg = r1 - r0;

    const int sw = tid >> 5, ln = tid & 31;
    if (sw < 4) {
        int h = sw;
        float edn = ed[n * 4 + h];
        float mx = -1e30f;
        for (int e = ln; e < deg; e += 32) {
            int s = clampi(ss[r0 + e], 0, N_NODES - 1);
            float w = es[s * 4 + h] + edn;
            w = (w > 0.f) ? w : 0.2f * w;
            mx = fmaxf(mx, w);
        }
#pragma unroll
        for (int off = 16; off; off >>= 1) mx = fmaxf(mx, __shfl_xor(mx, off, 32));
        float sm = 0.f;
        for (int e = ln; e < deg; e += 32) {
            int s = clampi(ss[r0 + e], 0, N_NODES - 1);
            float w = es[s * 4 + h] + edn;
            w = (w > 0.f) ? w : 0.2f * w;
            sm += expf(w - mx);
        }
#pragma unroll
        for (int off = 16; off; off >>= 1) sm += __shfl_xor(sm, off, 32);
        if (ln == 0) { smx[h] = mx; sinv[h] = 1.f / fmaxf(sm, 1e-16f); sed[h] = edn; }
    }
    __syncthreads();

    const int k  = tid & 63;
    const int hh = tid >> 6;
    float acc = 0.f;

    for (int e0 = 0; e0 < deg; e0 += 64) {
        int ce = min(64, deg - e0);
        __syncthreads();
        if (tid < ce * 4) {
            int e = tid >> 2, h = tid & 3;
            int s = clampi(ss[r0 + e0 + e], 0, N_NODES - 1);
            float w = es[s * 4 + h] + sed[h];
            w = (w > 0.f) ? w : 0.2f * w;
            sal[e * 4 + h] = expf(w - smx[h]) * sinv[h];
            if (h == 0) ssrc[e] = s;
        }
        __syncthreads();
        for (int e = 0; e < ce; ++e) {
            int s = ssrc[e];
            float xv = (float)A2[(size_t)s * KA + 256 + k];
            acc += sal[e * 4 + hh] * xv;
        }
    }
    A2[(size_t)n * KA + hh * 64 + k] = (bf16)acc;
}

// layers 2/3 logits on h (wave per node)
template <int H, int C>
__global__ __launch_bounds__(256) void k_logits(const bf16* __restrict__ G,
                                                const bf16* __restrict__ as_,
                                                const bf16* __restrict__ ad_,
                                                float* __restrict__ es, float* __restrict__ ed)
{
    const int wave = threadIdx.x >> 6;
    const int lane = threadIdx.x & 63;
    const int n = blockIdx.x * 4 + wave;
    if (n >= N_NODES) return;

#pragma unroll
    for (int h = 0; h < H; ++h) {
        float s = 0.f, d = 0.f;
        if constexpr (C == 256) {
            bf16x4 g  = *(const bf16x4*)(G + (size_t)n * SG + h * 256 + lane * 4);
            bf16x4 av = *(const bf16x4*)(as_ + h * 256 + lane * 4);
            bf16x4 dv = *(const bf16x4*)(ad_ + h * 256 + lane * 4);
#pragma unroll
            for (int j = 0; j < 4; ++j) {
                float gv = (float)g[j];
                s += gv * (float)av[j];
                d += gv * (float)dv[j];
            }
        } else {
            for (int c = lane; c < C; c += 64) {
                float hv = (float)G[(size_t)n * SG + h * C + c];
                s += hv * (float)as_[h * C + c];
                d += hv * (float)ad_[h * C + c];
            }
        }
#pragma unroll
        for (int off = 32; off; off >>= 1) {
            s += __shfl_xor(s, off);
            d += __shfl_xor(d, off);
        }
        if (lane == 0) { es[n * H + h] = s; ed[n * H + h] = d; }
    }
}

// Fused per-dst-node softmax + gather-aggregate + bias + skip (+mean/ELU).
// alpha LDS reads hoisted: 1 read (C%4==0) or 2 reads + selects per edge.
template <int H, int C, bool MEAN, bool ELU, bool EXTOUT>
__global__ __launch_bounds__(256) void k_agg(const bf16* __restrict__ G,
                                             const bf16* __restrict__ S,
                                             const float* __restrict__ es,
                                             const float* __restrict__ ed,
                                             const int* __restrict__ rp,
                                             const int* __restrict__ ss,
                                             const bf16* __restrict__ bgat,
                                             const bf16* __restrict__ bskip,
                                             void* __restrict__ out, int sout,
                                             const int* __restrict__ flags)
{
    constexpr int D  = H * C;
    constexpr int NV = (D + 3) / 4;
    constexpr int CH = 64;
    __shared__ float smx[H], sinv[H], sed[H];
    __shared__ float sal[CH * H];
    __shared__ int   ssrc[CH];

    const int n   = blockIdx.x;
    const int tid = threadIdx.x;
    int r0 = clampi(rp[n], 0, E2);
    int r1 = clampi(rp[n + 1], r0, E2);
    const int deg = r1 - r0;

    const int sw = tid >> 5, ln = tid & 31;
    for (int h = sw; h < H; h += 8) {
        float edn = ed[n * H + h];
        float mx = -1e30f;
        for (int e = ln; e < deg; e += 32) {
            int s = clampi(ss[r0 + e], 0, N_NODES - 1);
            float w = es[s * H + h] + edn;
            w = (w > 0.f) ? w : 0.2f * w;
            mx = fmaxf(mx, w);
        }
#pragma unroll
        for (int off = 16; off; off >>= 1) mx = fmaxf(mx, __shfl_xor(mx, off, 32));
        float sm = 0.f;
        for (int e = ln; e < deg; e += 32) {
            int s = clampi(ss[r0 + e], 0, N_NODES - 1);
            float w = es[s * H + h] + edn;
            w = (w > 0.f) ? w : 0.2f * w;
            sm += expf(w - mx);
        }
#pragma unroll
        for (int off = 16; off; off >>= 1) sm += __shfl_xor(sm, off, 32);
        if (ln == 0) { smx[h] = mx; sinv[h] = 1.f / fmaxf(sm, 1e-16f); sed[h] = edn; }
    }
    __syncthreads();

    const int c0 = tid * 4;
    const int hA = (c0 < D) ? (c0 / C) : 0;           // head of channel c0
    const int hB = (c0 + 3 < D) ? ((c0 + 3) / C) : hA; // head of channel c0+3
    int hj1 = ((c0 + 1 < D) ? ((c0 + 1) / C) : hA) == hA;
    int hj2 = ((c0 + 2 < D) ? ((c0 + 2) / C) : hA) == hA;
    const bool active = (tid < NV);

    float acc[4] = {0.f, 0.f, 0.f, 0.f};

    for (int e0 = 0; e0 < deg; e0 += CH) {
        int ce = min(CH, deg - e0);
        __syncthreads();
        for (int t = tid; t < ce * H; t += 256) {
            int e = t / H, h = t - e * H;
            int s = clampi(ss[r0 + e0 + e], 0, N_NODES - 1);
            float w = es[s * H + h] + sed[h];
            w = (w > 0.f) ? w : 0.2f * w;
            sal[e * H + h] = expf(w - smx[h]) * sinv[h];
            if (h == 0) ssrc[e] = s;
        }
        __syncthreads();
        if (active) {
            for (int e = 0; e < ce; ++e) {
                int s = ssrc[e];
                bf16x4 g = *(const bf16x4*)(G + (size_t)s * SG + c0);
                if constexpr (C % 4 == 0) {
                    float a = sal[e * H + hA];
#pragma unroll
                    for (int j = 0; j < 4; ++j)
                        acc[j] += a * (float)g[j];
                } else {
                    float aLo = sal[e * H + hA];
                    float aHi = sal[e * H + hB];
                    acc[0] += aLo * (float)g[0];
                    acc[1] += (hj1 ? aLo : aHi) * (float)g[1];
                    acc[2] += (hj2 ? aLo : aHi) * (float)g[2];
                    acc[3] += aHi * (float)g[3];
                }
            }
        }
    }

    const int outbf = EXTOUT ? flags[1] : 1;

    if constexpr (!MEAN) {
        if (active) {
            bf16x4 bg = *(const bf16x4*)(bgat + c0);
            bf16x4 sk = *(const bf16x4*)(S + (size_t)n * SG + c0);
            bf16x4 bs = *(const bf16x4*)(bskip + c0);
            bf16x4 ov;
#pragma unroll
            for (int j = 0; j < 4; ++j) {
                float v = acc[j] + (float)bg[j] + (float)sk[j] + (float)bs[j];
                if (ELU) v = (v > 0.f) ? v : (expf(v) - 1.f);
                ov[j] = (bf16)v;
            }
            *(bf16x4*)((bf16*)out + (size_t)n * sout + c0) = ov;
        }
    } else {
        __shared__ float sagg[D];
        if (active) {
#pragma unroll
            for (int j = 0; j < 4; ++j) {
                int c = c0 + j;
                if (c < D) sagg[c] = acc[j];
            }
        }
        __syncthreads();
        for (int c = tid; c < C; c += 256) {
            float v = 0.f;
#pragma unroll
            for (int h = 0; h < H; ++h) v += sagg[h * C + c];
            v *= (1.f / H);
            v += (float)bgat[c] + (float)S[(size_t)n * SG + c] + (float)bskip[c];
            if (outbf) ((bf16*)out)[(size_t)n * sout + c] = (bf16)v;
            else       ((float*)out)[(size_t)n * sout + c] = v;
        }
    }
}

// ----------------------------------------------------------------- launch ---
extern "C" void kernel_launch(void* const* d_in, const int* in_sizes, int n_in,
                              void* d_out, int out_size, void* d_ws, size_t ws_size,
                              hipStream_t stream)
{
    const void* x   = d_in[0];
    const int*  ei  = (const int*)d_in[1];
    const void* W1  = d_in[2];
    const void* Wl1 = d_in[6];
    const void* W2  = d_in[8];
    const void* Wl2 = d_in[12];
    const void* W3  = d_in[14];
    const void* Wl3 = d_in[18];

    P12 ps;
    ps.s[0] = d_in[3];  ps.s[1] = d_in[4];  ps.s[2] = d_in[5];  ps.s[3] = d_in[7];
    ps.s[4] = d_in[9];  ps.s[5] = d_in[10]; ps.s[6] = d_in[11]; ps.s[7] = d_in[13];
    ps.s[8] = d_in[15]; ps.s[9] = d_in[16]; ps.s[10] = d_in[17]; ps.s[11] = d_in[19];

    char* w = (char*)d_ws;
    auto alloc = [&](size_t bytes) {
        char* p = w;
        w += (bytes + 255) & ~(size_t)255;
        return p;
    };
    int*   flags = (int*)alloc(64);
    int*   cnt   = (int*)alloc((size_t)N_NODES * 4);
    int*   rp    = (int*)alloc((size_t)(N_NODES + 1) * 4);
    int*   cur   = (int*)alloc((size_t)N_NODES * 4);
    int*   ss    = (int*)alloc((size_t)E2 * 4);
    float* es    = (float*)alloc((size_t)N_NODES * 6 * 4);
    float* ed    = (float*)alloc((size_t)N_NODES * 6 * 4);
    bf16*  pool  = (bf16*)alloc((size_t)PO_END * 2);
    float* ws1   = (float*)alloc((size_t)64 * 4 * 4);
    float* wd1   = (float*)alloc((size_t)64 * 4 * 4);
    bf16*  bsum  = (bf16*)alloc((size_t)D1 * 2);
    bf16*  Bt    = (bf16*)alloc((size_t)NP12 * 1024 * 2);
    bf16*  X     = (bf16*)alloc((size_t)N_NODES * D1 * 2);   // x1/x2
    bf16*  WS    = (bf16*)alloc((size_t)N_NODES * SG * 2);   // GEMM out [gat|skip]
    bf16*  A2    = WS;   // layer-1 A'' [N x KA] aliases WS (dead during layer 1)

    k_detect<<<1, 64, 0, stream>>>(ei, (const unsigned short*)x, flags);

    hipMemsetAsync(cnt, 0, N_NODES * 4, stream);
    k_count<<<(E2 + 255) / 256, 256, 0, stream>>>(ei, cnt, flags);
    k_scan<<<1, 256, 0, stream>>>(cnt, rp);
    k_copy<<<(N_NODES + 255) / 256, 256, 0, stream>>>(rp, cur);
    k_fill<<<(E2 + 255) / 256, 256, 0, stream>>>(ei, cur, ss, flags);

    k_params<<<(PO_END + 255) / 256, 256, 0, stream>>>(ps, pool, flags);

    const dim3 blk(256);
    const int MT = (N_NODES + 127) / 128;   // 157

    // ---- layer 1 (restructured): aggregate x, then fused GEMM K=320
    k_veca<<<64, 256, 0, stream>>>(W1, ps.s[0], ps.s[1], ps.s[2], ps.s[3],
                                   ws1, wd1, bsum, flags);
    k_padx<<<(N_NODES * 64 + 255) / 256, 256, 0, stream>>>(x, A2, flags);
    k_wfuse1<<<(D1 * KA + 255) / 256, 256, 0, stream>>>(W1, Wl1, Bt, flags);
    k_logits1<<<N_NODES / 4, 256, 0, stream>>>(A2, ws1, wd1, es, ed);
    k_aggx<<<N_NODES, 256, 0, stream>>>(A2, es, ed, rp, ss);
    k_gemm<true><<<MT * (D1 / 128), blk, 0, stream>>>(A2, Bt, X, N_NODES, KA, KA, KA, D1,
                                                      MT, D1 / 128, bsum);   // x1 = ELU(...)

    // ---- layer 2: K=1024, out 2048 = [GAT 1024 | skip 1024]
    k_wcatT<<<dim3(16, NP12 / 64), blk, 0, stream>>>(W2, Wl2, Bt, 1024, 1024, 1024, flags);
    k_gemm<false><<<MT * (NP12 / 128), blk, 0, stream>>>(X, Bt, WS, N_NODES, 1024, 1024, 1024, SG,
                                                         MT, NP12 / 128, nullptr);
    k_logits<4, 256><<<N_NODES / 4, 256, 0, stream>>>(WS, pool + PO_A2S, pool + PO_A2D, es, ed);
    k_agg<4, 256, false, true, false><<<N_NODES, 256, 0, stream>>>(
        WS, WS + D1, es, ed, rp, ss, pool + PO_B2, pool + PO_BL2, X, D1, flags);

    // ---- layer 3: K=1024, out 896 = [GAT 726 | skip 121 | pad]
    k_wcatT<<<dim3(16, NP3 / 64), blk, 0, stream>>>(W3, Wl3, Bt, 726, 726, 121, flags);
    k_gemm<false><<<MT * (NP3 / 128), blk, 0, stream>>>(X, Bt, WS, N_NODES, 1024, 1024, 1024, SG,
                                                        MT, NP3 / 128, nullptr);
    k_logits<6, 121><<<N_NODES / 4, 256, 0, stream>>>(WS, pool + PO_A3S, pool + PO_A3D, es, ed);
    k_agg<6, 121, true, false, true><<<N_NODES, 256, 0, stream>>>(
        WS, WS + 726, es, ed, rp, ss, pool + PO_B3, pool + PO_BL3, d_out, 121, flags);
}

// Round 9
// 656.348 us; speedup vs baseline: 1.0932x; 1.0087x over previous
//
#include <hip/hip_runtime.h>
#include <hip/hip_bf16.h>
#include <math.h>

typedef __bf16 bf16;
typedef __attribute__((ext_vector_type(4))) __bf16 bf16x4;
typedef __attribute__((ext_vector_type(8))) __bf16 bf16x8;
typedef __attribute__((ext_vector_type(4))) float f32x4;

#define N_NODES 20000
#define N_EDGES 320000
#define E2 (N_EDGES + N_NODES)   // 340000 edges incl self-loops
#define F_IN 50
#define D1 1024                  // H1*C1
#define NP12 2048                // padded GEMM out-cols, layer 2 ([W|Wl])
#define NP3 896                  // padded GEMM out-cols, layer 3 (726+121=847 -> 896)
#define SG 2048                  // row stride of GEMM output buffer
#define KA 320                   // layer-1 fused K: 4*64 aggx + 64 x

// params pool element offsets (bf16 pool)
#define PO_A1S 0
#define PO_A1D 1024
#define PO_B1  2048
#define PO_BL1 3072
#define PO_A2S 4096
#define PO_A2D 5120
#define PO_B2  6144
#define PO_BL2 7168
#define PO_A3S 8192
#define PO_A3D 8918
#define PO_B3  9644
#define PO_BL3 9765
#define PO_END 9886

__device__ __forceinline__ int clampi(int v, int lo, int hi)
{
    return v < lo ? lo : (v > hi ? hi : v);
}

__device__ __forceinline__ float loadf(const void* p, long idx, int isb)
{
    return isb ? (float)((const bf16*)p)[idx] : ((const float*)p)[idx];
}

__device__ __forceinline__ int loadei(const int* ei, long idx, int i64)
{
    return i64 ? ei[2 * idx] : ei[idx];
}

// --------------------------------------------------------------- detect -----
__global__ void k_detect(const int* __restrict__ ei,
                         const unsigned short* __restrict__ xw,
                         int* __restrict__ flags)
{
    if (blockIdx.x != 0 || threadIdx.x != 0) return;
    int allz = 1;
    for (int i = 0; i < 128; ++i)
        if (ei[2 * i + 1] != 0) { allz = 0; break; }
    int inr = 0;
    for (int i = 0; i < 128; ++i) {
        int e = (xw[2 * i] >> 7) & 0xFF;
        if (e >= 100 && e <= 140) inr++;
    }
    flags[0] = allz;
    flags[1] = (inr >= 64) ? 1 : 0;
}

// ---------------------------------------------------------------- GEMM ------
// m97-style 128x128 tile, BK=64, global_load_lds width-16, XCD swizzle,
// XOR k-chunk LDS swizzle. BACT (compile-time): fused bias+ELU epilogue.
template <bool BACT>
__global__ __launch_bounds__(256) void k_gemm(const bf16* __restrict__ A,
                                              const bf16* __restrict__ Bt,
                                              bf16* __restrict__ C,
                                              int M, int K, int lda, int ldb, int ldc,
                                              int mtiles, int ntiles,
                                              const bf16* __restrict__ bias)
{
    __shared__ bf16 As[128 * 64];
    __shared__ bf16 Bs[128 * 64];

    int id = blockIdx.x;
    int gfull = mtiles >> 3;
    int base  = gfull * 8 * ntiles;
    int x, y;
    if (id < base) {
        int gsz = 8 * ntiles;
        int g = id / gsz;
        int r = id - g * gsz;
        x = g * 8 + (r & 7);
        y = r >> 3;
    } else {
        int rem = mtiles - (gfull << 3);
        int r = id - base;
        x = (gfull << 3) + r % rem;
        y = r / rem;
    }
    const int m0 = x * 128;
    const int n0 = y * 128;

    const int tid  = threadIdx.x;
    const int wave = tid >> 6;
    const int lane = tid & 63;
    const int wm   = (wave >> 1) * 64;
    const int wn   = (wave & 1) * 64;
    const int frow  = lane & 15;

    const int srow = wave * 32 + (lane >> 3);
    const int scol = (((lane & 7) ^ (lane >> 3)) * 8);

    f32x4 acc[4][4];
#pragma unroll
    for (int i = 0; i < 4; ++i)
#pragma unroll
        for (int j = 0; j < 4; ++j)
#pragma unroll
            for (int r = 0; r < 4; ++r) acc[i][j][r] = 0.f;

    for (int k0 = 0; k0 < K; k0 += 64) {
#pragma unroll
        for (int i = 0; i < 4; ++i) {
            int ra = srow + i * 8;
            int ga = m0 + ra; if (ga > M - 1) ga = M - 1;   // junk rows -> discarded C rows
            __builtin_amdgcn_global_load_lds(
                (const __attribute__((address_space(1))) void*)(A + (size_t)ga * lda + k0 + scol),
                (__attribute__((address_space(3))) void*)(As + wave * 2048 + i * 512),
                16, 0, 0);
            int gb = n0 + ra;
            __builtin_amdgcn_global_load_lds(
                (const __attribute__((address_space(1))) void*)(Bt + (size_t)gb * ldb + k0 + scol),
                (__attribute__((address_space(3))) void*)(Bs + wave * 2048 + i * 512),
                16, 0, 0);
        }
        __syncthreads();
#pragma unroll
        for (int kk = 0; kk < 2; ++kk) {
            const int coff = (((kk * 4 + (lane >> 4)) ^ (frow & 7)) << 3);
            bf16x8 af[4], bfr[4];
#pragma unroll
            for (int i = 0; i < 4; ++i) {
                af[i]  = *(const bf16x8*)(As + (wm + i * 16 + frow) * 64 + coff);
                bfr[i] = *(const bf16x8*)(Bs + (wn + i * 16 + frow) * 64 + coff);
            }
#pragma unroll
            for (int i = 0; i < 4; ++i)
#pragma unroll
                for (int j = 0; j < 4; ++j)
                    acc[i][j] = __builtin_amdgcn_mfma_f32_16x16x32_bf16(af[i], bfr[j], acc[i][j], 0, 0, 0);
        }
        __syncthreads();
    }

#pragma unroll
    for (int i = 0; i < 4; ++i) {
#pragma unroll
        for (int j = 0; j < 4; ++j) {
            int rbase = m0 + wm + i * 16 + (lane >> 4) * 4;
            int col   = n0 + wn + j * 16 + frow;
            if constexpr (BACT) {
                float bv = (float)bias[col];
#pragma unroll
                for (int r = 0; r < 4; ++r) {
                    int row = rbase + r;
                    if (row < M) {
                        float v = acc[i][j][r] + bv;
                        v = (v > 0.f) ? v : (expf(v) - 1.f);
                        C[(size_t)row * ldc + col] = (bf16)v;
                    }
                }
            } else {
#pragma unroll
                for (int r = 0; r < 4; ++r) {
                    int row = rbase + r;
                    if (row < M) C[(size_t)row * ldc + col] = (bf16)acc[i][j][r];
                }
            }
        }
    }
}

// ------------------------------------------------------------ prep kernels --
// x -> A2[n*KA + 256 + k] (padded to 64)
__global__ void k_padx(const void* __restrict__ x, bf16* __restrict__ A2,
                       const int* __restrict__ flags)
{
    int idx = blockIdx.x * 256 + threadIdx.x;
    if (idx >= N_NODES * 64) return;
    int isb = flags[1];
    int n = idx >> 6, k = idx & 63;
    A2[(size_t)n * KA + 256 + k] = (k < F_IN) ? (bf16)loadf(x, (long)n * F_IN + k, isb)
                                              : (bf16)0.f;
}

// ws[k][h] = sum_c W1[k, h*256+c]*a1s[h,c]; wd likewise; bsum = b1+bl1.
// grid 64 blocks (one per k); head h = wave, 64-lane wave reduction.
__global__ __launch_bounds__(256) void k_veca(const void* __restrict__ W1,
                                              const void* __restrict__ a1s,
                                              const void* __restrict__ a1d,
                                              const void* __restrict__ b1,
                                              const void* __restrict__ bl1,
                                              float* __restrict__ ws, float* __restrict__ wd,
                                              bf16* __restrict__ bsum,
                                              const int* __restrict__ flags)
{
    const int isb = flags[1];
    const int k = blockIdx.x;          // 0..63
    const int h = threadIdx.x >> 6;
    const int c0 = threadIdx.x & 63;
    float s = 0.f, d = 0.f;
    if (k < F_IN) {
        for (int c = c0; c < 256; c += 64) {
            float wv = loadf(W1, (long)k * D1 + h * 256 + c, isb);
            s += wv * loadf(a1s, h * 256 + c, isb);
            d += wv * loadf(a1d, h * 256 + c, isb);
        }
    }
#pragma unroll
    for (int off = 32; off; off >>= 1) {
        s += __shfl_xor(s, off);
        d += __shfl_xor(d, off);
    }
    if (c0 == 0) { ws[k * 4 + h] = s; wd[k * 4 + h] = d; }
    if (k < 4) {
        int j = k * 256 + threadIdx.x;
        bsum[j] = (bf16)(loadf(b1, j, isb) + loadf(bl1, j, isb));
    }
}

// fused layer-1 B^T [1024 x KA]: k'<256 blockdiag(W1), k'>=256 Wl1
__global__ void k_wfuse1(const void* __restrict__ W1, const void* __restrict__ Wl1,
                         bf16* __restrict__ Bt, const int* __restrict__ flags)
{
    int idx = blockIdx.x * 256 + threadIdx.x;
    if (idx >= D1 * KA) return;
    int isb = flags[1];
    int j = idx / KA;
    int kp = idx - j * KA;
    float v = 0.f;
    if (kp < 256) {
        int hp = kp >> 6, k = kp & 63;
        if ((j >> 8) == hp && k < F_IN) v = loadf(W1, (long)k * D1 + j, isb);
    } else {
        int k = kp - 256;
        if (k < F_IN) v = loadf(Wl1, (long)k * D1 + j, isb);
    }
    Bt[idx] = (bf16)v;
}

// Tiled transpose-concat: Bt[n][k] = [Wa | Wb | 0](k, n), K=1024 rows.
__global__ __launch_bounds__(256) void k_wcatT(const void* __restrict__ Wa,
                                               const void* __restrict__ Wb,
                                               bf16* __restrict__ Bt,
                                               int split, int da, int db,
                                               const int* __restrict__ flags)
{
    __shared__ bf16 T[64][65];
    const int isb = flags[1];
    const int k0 = blockIdx.x * 64;
    const int n0 = blockIdx.y * 64;
    const int r = threadIdx.x >> 6;    // 0..3
    const int c = threadIdx.x & 63;
    const int n = n0 + c;
#pragma unroll
    for (int kk = 0; kk < 16; ++kk) {
        int k = k0 + r + kk * 4;
        float v = 0.f;
        if (n < split)           v = loadf(Wa, (long)k * da + n, isb);
        else if (n < split + db) v = loadf(Wb, (long)k * db + (n - split), isb);
        T[r + kk * 4][c] = (bf16)v;
    }
    __syncthreads();
#pragma unroll
    for (int kk = 0; kk < 16; ++kk) {
        int nn = r + kk * 4;
        Bt[(size_t)(n0 + nn) * 1024 + k0 + c] = T[c][nn];
    }
}

struct P12 { const void* s[12]; };

__global__ void k_params(P12 ps, bf16* __restrict__ pool, const int* __restrict__ flags)
{
    const int off[13] = {PO_A1S, PO_A1D, PO_B1, PO_BL1, PO_A2S, PO_A2D, PO_B2,
                         PO_BL2, PO_A3S, PO_A3D, PO_B3, PO_BL3, PO_END};
    int idx = blockIdx.x * 256 + threadIdx.x;
    if (idx >= PO_END) return;
    int isb = flags[1];
    int seg = 0;
    while (idx >= off[seg + 1]) seg++;
    pool[idx] = (bf16)loadf(ps.s[seg], idx - off[seg], isb);
}

// ------------------------------------------------------------- CSR build ----
__global__ void k_count(const int* __restrict__ ei, int* __restrict__ cnt,
                        const int* __restrict__ flags)
{
    int e = blockIdx.x * 256 + threadIdx.x;
    if (e >= E2) return;
    int i64 = flags[0];
    int d = (e < N_EDGES) ? loadei(ei, (long)N_EDGES + e, i64) : (e - N_EDGES);
    d = clampi(d, 0, N_NODES - 1);
    atomicAdd(&cnt[d], 1);
}

__global__ __launch_bounds__(256) void k_scan(const int* __restrict__ cnt, int* __restrict__ rp)
{
    __shared__ int ssum[256];
    int tid = threadIdx.x;
    const int chunk = (N_NODES + 255) / 256;
    int lo = tid * chunk;
    int hi = lo + chunk; if (hi > N_NODES) hi = N_NODES;
    int s = 0;
    for (int i = lo; i < hi; ++i) s += cnt[i];
    ssum[tid] = s;
    __syncthreads();
    if (tid == 0) {
        int run = 0;
        for (int i = 0; i < 256; ++i) { int t = ssum[i]; ssum[i] = run; run += t; }
        rp[N_NODES] = run;
    }
    __syncthreads();
    int run = ssum[tid];
    for (int i = lo; i < hi; ++i) { rp[i] = run; run += cnt[i]; }
}

__global__ void k_copy(const int* __restrict__ rp, int* __restrict__ cur)
{
    int i = blockIdx.x * 256 + threadIdx.x;
    if (i < N_NODES) cur[i] = rp[i];
}

__global__ void k_fill(const int* __restrict__ ei, int* __restrict__ cur,
                       int* __restrict__ ss, const int* __restrict__ flags)
{
    int e = blockIdx.x * 256 + threadIdx.x;
    if (e >= E2) return;
    int i64 = flags[0];
    int s, d;
    if (e < N_EDGES) {
        s = loadei(ei, e, i64);
        d = loadei(ei, (long)N_EDGES + e, i64);
    } else {
        s = e - N_EDGES; d = s;
    }
    s = clampi(s, 0, N_NODES - 1);
    d = clampi(d, 0, N_NODES - 1);
    int pos = atomicAdd(&cur[d], 1);
    if (pos >= 0 && pos < E2) ss[pos] = s;
}

// ----------------------------------------------------- attention kernels ----
// layer-1 logits: es[n,h] = sum_k x[n,k]*ws[k,h] (wave per node)
__global__ __launch_bounds__(256) void k_logits1(const bf16* __restrict__ A2,
                                                 const float* __restrict__ ws,
                                                 const float* __restrict__ wd,
                                                 float* __restrict__ es, float* __restrict__ ed)
{
    const int wave = threadIdx.x >> 6;
    const int lane = threadIdx.x & 63;
    const int n = blockIdx.x * 4 + wave;
    if (n >= N_NODES) return;
    float xv = (float)A2[(size_t)n * KA + 256 + lane];
    f32x4 wsv = *(const f32x4*)(ws + lane * 4);
    f32x4 wdv = *(const f32x4*)(wd + lane * 4);
    float s[4], d[4];
#pragma unroll
    for (int h = 0; h < 4; ++h) { s[h] = xv * wsv[h]; d[h] = xv * wdv[h]; }
#pragma unroll
    for (int off = 32; off; off >>= 1)
#pragma unroll
        for (int h = 0; h < 4; ++h) {
            s[h] += __shfl_xor(s[h], off);
            d[h] += __shfl_xor(d[h], off);
        }
    if (lane == 0) {
#pragma unroll
        for (int h = 0; h < 4; ++h) { es[n * 4 + h] = s[h]; ed[n * 4 + h] = d[h]; }
    }
}

// layer-1 aggregate: aggx[n,h,k] = sum_e alpha[e,h] x[src_e,k] (block per node)
__global__ __launch_bounds__(256) void k_aggx(bf16* __restrict__ A2,
                                              const float* __restrict__ es,
                                              const float* __restrict__ ed,
                                              const int* __restrict__ rp,
                                              const int* __restrict__ ss)
{
    __shared__ float smx[4], sinv[4], sed[4];
    __shared__ float sal[64 * 4];
    __shared__ int   ssrc[64];

    const int n   = blockIdx.x;
    const int tid = threadIdx.x;
    int r0 = clampi(rp[n], 0, E2);
    int r1 = clampi(rp[n + 1], r0, E2);
    const int deg = r1 - r0;

    const int sw = tid >> 5, ln = tid & 31;
    if (sw < 4) {
        int h = sw;
        float edn = ed[n * 4 + h];
        float mx = -1e30f;
        for (int e = ln; e < deg; e += 32) {
            int s = clampi(ss[r0 + e], 0, N_NODES - 1);
            float w = es[s * 4 + h] + edn;
            w = (w > 0.f) ? w : 0.2f * w;
            mx = fmaxf(mx, w);
        }
#pragma unroll
        for (int off = 16; off; off >>= 1) mx = fmaxf(mx, __shfl_xor(mx, off, 32));
        float sm = 0.f;
        for (int e = ln; e < deg; e += 32) {
            int s = clampi(ss[r0 + e], 0, N_NODES - 1);
            float w = es[s * 4 + h] + edn;
            w = (w > 0.f) ? w : 0.2f * w;
            sm += expf(w - mx);
        }
#pragma unroll
        for (int off = 16; off; off >>= 1) sm += __shfl_xor(sm, off, 32);
        if (ln == 0) { smx[h] = mx; sinv[h] = 1.f / fmaxf(sm, 1e-16f); sed[h] = edn; }
    }
    __syncthreads();

    const int k  = tid & 63;
    const int hh = tid >> 6;
    float acc = 0.f;

    for (int e0 = 0; e0 < deg; e0 += 64) {
        int ce = min(64, deg - e0);
        __syncthreads();
        if (tid < ce * 4) {
            int e = tid >> 2, h = tid & 3;
            int s = clampi(ss[r0 + e0 + e], 0, N_NODES - 1);
            float w = es[s * 4 + h] + sed[h];
            w = (w > 0.f) ? w : 0.2f * w;
            sal[e * 4 + h] = expf(w - smx[h]) * sinv[h];
            if (h == 0) ssrc[e] = s;
        }
        __syncthreads();
        for (int e = 0; e < ce; ++e) {
            int s = ssrc[e];
            float xv = (float)A2[(size_t)s * KA + 256 + k];
            acc += sal[e * 4 + hh] * xv;
        }
    }
    A2[(size_t)n * KA + hh * 64 + k] = (bf16)acc;
}

// layers 2/3 logits on h (wave per node)
template <int H, int C>
__global__ __launch_bounds__(256) void k_logits(const bf16* __restrict__ G,
                                                const bf16* __restrict__ as_,
                                                const bf16* __restrict__ ad_,
                                                float* __restrict__ es, float* __restrict__ ed)
{
    const int wave = threadIdx.x >> 6;
    const int lane = threadIdx.x & 63;
    const int n = blockIdx.x * 4 + wave;
    if (n >= N_NODES) return;

#pragma unroll
    for (int h = 0; h < H; ++h) {
        float s = 0.f, d = 0.f;
        if constexpr (C == 256) {
            bf16x4 g  = *(const bf16x4*)(G + (size_t)n * SG + h * 256 + lane * 4);
            bf16x4 av = *(const bf16x4*)(as_ + h * 256 + lane * 4);
            bf16x4 dv = *(const bf16x4*)(ad_ + h * 256 + lane * 4);
#pragma unroll
            for (int j = 0; j < 4; ++j) {
                float gv = (float)g[j];
                s += gv * (float)av[j];
                d += gv * (float)dv[j];
            }
        } else {
            for (int c = lane; c < C; c += 64) {
                float hv = (float)G[(size_t)n * SG + h * C + c];
                s += hv * (float)as_[h * C + c];
                d += hv * (float)ad_[h * C + c];
            }
        }
#pragma unroll
        for (int off = 32; off; off >>= 1) {
            s += __shfl_xor(s, off);
            d += __shfl_xor(d, off);
        }
        if (lane == 0) { es[n * H + h] = s; ed[n * H + h] = d; }
    }
}

// Fused per-dst-node softmax + gather-aggregate + bias + skip (+mean/ELU).
// Phase 2: 4-wide edge grouping -> 4 independent global loads in flight/wave.
template <int H, int C, bool MEAN, bool ELU, bool EXTOUT>
__global__ __launch_bounds__(256) void k_agg(const bf16* __restrict__ G,
                                             const bf16* __restrict__ S,
                                             const float* __restrict__ es,
                                             const float* __restrict__ ed,
                                             const int* __restrict__ rp,
                                             const int* __restrict__ ss,
                                             const bf16* __restrict__ bgat,
                                             const bf16* __restrict__ bskip,
                                             void* __restrict__ out, int sout,
                                             const int* __restrict__ flags)
{
    constexpr int D  = H * C;
    constexpr int NV = (D + 3) / 4;
    constexpr int CH = 256;
    __shared__ float smx[H], sinv[H], sed[H];
    __shared__ float sal[CH * H];
    __shared__ int   ssrc[CH];

    const int n   = blockIdx.x;
    const int tid = threadIdx.x;
    int r0 = clampi(rp[n], 0, E2);
    int r1 = clampi(rp[n + 1], r0, E2);
    const int deg = r1 - r0;

    const int sw = tid >> 5, ln = tid & 31;
    for (int h = sw; h < H; h += 8) {
        float edn = ed[n * H + h];
        float mx = -1e30f;
        for (int e = ln; e < deg; e += 32) {
            int s = clampi(ss[r0 + e], 0, N_NODES - 1);
            float w = es[s * H + h] + edn;
            w = (w > 0.f) ? w : 0.2f * w;
            mx = fmaxf(mx, w);
        }
#pragma unroll
        for (int off = 16; off; off >>= 1) mx = fmaxf(mx, __shfl_xor(mx, off, 32));
        float sm = 0.f;
        for (int e = ln; e < deg; e += 32) {
            int s = clampi(ss[r0 + e], 0, N_NODES - 1);
            float w = es[s * H + h] + edn;
            w = (w > 0.f) ? w : 0.2f * w;
            sm += expf(w - mx);
        }
#pragma unroll
        for (int off = 16; off; off >>= 1) sm += __shfl_xor(sm, off, 32);
        if (ln == 0) { smx[h] = mx; sinv[h] = 1.f / fmaxf(sm, 1e-16f); sed[h] = edn; }
    }
    __syncthreads();

    const int c0 = tid * 4;
    const int hA = (c0 < D) ? (c0 / C) : 0;            // head of channel c0
    const int hB = (c0 + 3 < D) ? ((c0 + 3) / C) : hA; // head of channel c0+3
    int hj1 = ((c0 + 1 < D) ? ((c0 + 1) / C) : hA) == hA;
    int hj2 = ((c0 + 2 < D) ? ((c0 + 2) / C) : hA) == hA;
    const bool active = (tid < NV);

    float acc[4] = {0.f, 0.f, 0.f, 0.f};

    for (int e0 = 0; e0 < deg; e0 += CH) {
        int ce = min(CH, deg - e0);
        __syncthreads();
        for (int t = tid; t < ce * H; t += 256) {
            int e = t / H, h = t - e * H;
            int s = clampi(ss[r0 + e0 + e], 0, N_NODES - 1);
            float w = es[s * H + h] + sed[h];
            w = (w > 0.f) ? w : 0.2f * w;
            sal[e * H + h] = expf(w - smx[h]) * sinv[h];
            if (h == 0) ssrc[e] = s;
        }
        __syncthreads();
        if (active) {
            for (int eb = 0; eb < ce; eb += 4) {
                int idx[4]; float zm[4];
#pragma unroll
                for (int p = 0; p < 4; ++p) {
                    int e = eb + p;
                    idx[p] = (e < ce) ? e : eb;
                    zm[p]  = (e < ce) ? 1.f : 0.f;
                }
                int sg[4];
#pragma unroll
                for (int p = 0; p < 4; ++p) sg[p] = ssrc[idx[p]];
                bf16x4 g[4];
#pragma unroll
                for (int p = 0; p < 4; ++p)
                    g[p] = *(const bf16x4*)(G + (size_t)sg[p] * SG + c0);
                if constexpr (C % 4 == 0) {
                    float a[4];
#pragma unroll
                    for (int p = 0; p < 4; ++p) a[p] = sal[idx[p] * H + hA] * zm[p];
#pragma unroll
                    for (int p = 0; p < 4; ++p)
#pragma unroll
                        for (int j = 0; j < 4; ++j)
                            acc[j] += a[p] * (float)g[p][j];
                } else {
                    float aL[4], aH[4];
#pragma unroll
                    for (int p = 0; p < 4; ++p) {
                        aL[p] = sal[idx[p] * H + hA] * zm[p];
                        aH[p] = sal[idx[p] * H + hB] * zm[p];
                    }
#pragma unroll
                    for (int p = 0; p < 4; ++p) {
                        acc[0] += aL[p] * (float)g[p][0];
                        acc[1] += (hj1 ? aL[p] : aH[p]) * (float)g[p][1];
                        acc[2] += (hj2 ? aL[p] : aH[p]) * (float)g[p][2];
                        acc[3] += aH[p] * (float)g[p][3];
                    }
                }
            }
        }
    }

    const int outbf = EXTOUT ? flags[1] : 1;

    if constexpr (!MEAN) {
        if (active) {
            bf16x4 bg = *(const bf16x4*)(bgat + c0);
            bf16x4 sk = *(const bf16x4*)(S + (size_t)n * SG + c0);
            bf16x4 bs = *(const bf16x4*)(bskip + c0);
            bf16x4 ov;
#pragma unroll
            for (int j = 0; j < 4; ++j) {
                float v = acc[j] + (float)bg[j] + (float)sk[j] + (float)bs[j];
                if (ELU) v = (v > 0.f) ? v : (expf(v) - 1.f);
                ov[j] = (bf16)v;
            }
            *(bf16x4*)((bf16*)out + (size_t)n * sout + c0) = ov;
        }
    } else {
        __shared__ float sagg[D];
        if (active) {
#pragma unroll
            for (int j = 0; j < 4; ++j) {
                int c = c0 + j;
                if (c < D) sagg[c] = acc[j];
            }
        }
        __syncthreads();
        for (int c = tid; c < C; c += 256) {
            float v = 0.f;
#pragma unroll
            for (int h = 0; h < H; ++h) v += sagg[h * C + c];
            v *= (1.f / H);
            v += (float)bgat[c] + (float)S[(size_t)n * SG + c] + (float)bskip[c];
            if (outbf) ((bf16*)out)[(size_t)n * sout + c] = (bf16)v;
            else       ((float*)out)[(size_t)n * sout + c] = v;
        }
    }
}

// ----------------------------------------------------------------- launch ---
extern "C" void kernel_launch(void* const* d_in, const int* in_sizes, int n_in,
                              void* d_out, int out_size, void* d_ws, size_t ws_size,
                              hipStream_t stream)
{
    const void* x   = d_in[0];
    const int*  ei  = (const int*)d_in[1];
    const void* W1  = d_in[2];
    const void* Wl1 = d_in[6];
    const void* W2  = d_in[8];
    const void* Wl2 = d_in[12];
    const void* W3  = d_in[14];
    const void* Wl3 = d_in[18];

    P12 ps;
    ps.s[0] = d_in[3];  ps.s[1] = d_in[4];  ps.s[2] = d_in[5];  ps.s[3] = d_in[7];
    ps.s[4] = d_in[9];  ps.s[5] = d_in[10]; ps.s[6] = d_in[11]; ps.s[7] = d_in[13];
    ps.s[8] = d_in[15]; ps.s[9] = d_in[16]; ps.s[10] = d_in[17]; ps.s[11] = d_in[19];

    char* w = (char*)d_ws;
    auto alloc = [&](size_t bytes) {
        char* p = w;
        w += (bytes + 255) & ~(size_t)255;
        return p;
    };
    int*   flags = (int*)alloc(64);
    int*   cnt   = (int*)alloc((size_t)N_NODES * 4);
    int*   rp    = (int*)alloc((size_t)(N_NODES + 1) * 4);
    int*   cur   = (int*)alloc((size_t)N_NODES * 4);
    int*   ss    = (int*)alloc((size_t)E2 * 4);
    float* es    = (float*)alloc((size_t)N_NODES * 6 * 4);
    float* ed    = (float*)alloc((size_t)N_NODES * 6 * 4);
    bf16*  pool  = (bf16*)alloc((size_t)PO_END * 2);
    float* ws1   = (float*)alloc((size_t)64 * 4 * 4);
    float* wd1   = (float*)alloc((size_t)64 * 4 * 4);
    bf16*  bsum  = (bf16*)alloc((size_t)D1 * 2);
    bf16*  Bt    = (bf16*)alloc((size_t)NP12 * 1024 * 2);
    bf16*  X     = (bf16*)alloc((size_t)N_NODES * D1 * 2);   // x1/x2
    bf16*  WS    = (bf16*)alloc((size_t)N_NODES * SG * 2);   // GEMM out [gat|skip]
    bf16*  A2    = WS;   // layer-1 A'' [N x KA] aliases WS (dead during layer 1)

    k_detect<<<1, 64, 0, stream>>>(ei, (const unsigned short*)x, flags);

    hipMemsetAsync(cnt, 0, N_NODES * 4, stream);
    k_count<<<(E2 + 255) / 256, 256, 0, stream>>>(ei, cnt, flags);
    k_scan<<<1, 256, 0, stream>>>(cnt, rp);
    k_copy<<<(N_NODES + 255) / 256, 256, 0, stream>>>(rp, cur);
    k_fill<<<(E2 + 255) / 256, 256, 0, stream>>>(ei, cur, ss, flags);

    k_params<<<(PO_END + 255) / 256, 256, 0, stream>>>(ps, pool, flags);

    const dim3 blk(256);
    const int MT = (N_NODES + 127) / 128;   // 157

    // ---- layer 1 (restructured): aggregate x, then fused GEMM K=320
    k_veca<<<64, 256, 0, stream>>>(W1, ps.s[0], ps.s[1], ps.s[2], ps.s[3],
                                   ws1, wd1, bsum, flags);
    k_padx<<<(N_NODES * 64 + 255) / 256, 256, 0, stream>>>(x, A2, flags);
    k_wfuse1<<<(D1 * KA + 255) / 256, 256, 0, stream>>>(W1, Wl1, Bt, flags);
    k_logits1<<<N_NODES / 4, 256, 0, stream>>>(A2, ws1, wd1, es, ed);
    k_aggx<<<N_NODES, 256, 0, stream>>>(A2, es, ed, rp, ss);
    k_gemm<true><<<MT * (D1 / 128), blk, 0, stream>>>(A2, Bt, X, N_NODES, KA, KA, KA, D1,
                                                      MT, D1 / 128, bsum);   // x1 = ELU(...)

    // ---- layer 2: K=1024, out 2048 = [GAT 1024 | skip 1024]
    k_wcatT<<<dim3(16, NP12 / 64), blk, 0, stream>>>(W2, Wl2, Bt, 1024, 1024, 1024, flags);
    k_gemm<false><<<MT * (NP12 / 128), blk, 0, stream>>>(X, Bt, WS, N_NODES, 1024, 1024, 1024, SG,
                                                         MT, NP12 / 128, nullptr);
    k_logits<4, 256><<<N_NODES / 4, 256, 0, stream>>>(WS, pool + PO_A2S, pool + PO_A2D, es, ed);
    k_agg<4, 256, false, true, false><<<N_NODES, 256, 0, stream>>>(
        WS, WS + D1, es, ed, rp, ss, pool + PO_B2, pool + PO_BL2, X, D1, flags);

    // ---- layer 3: K=1024, out 896 = [GAT 726 | skip 121 | pad]
    k_wcatT<<<dim3(16, NP3 / 64), blk, 0, stream>>>(W3, Wl3, Bt, 726, 726, 121, flags);
    k_gemm<false><<<MT * (NP3 / 128), blk, 0, stream>>>(X, Bt, WS, N_NODES, 1024, 1024, 1024, SG,
                                                        MT, NP3 / 128, nullptr);
    k_logits<6, 121><<<N_NODES / 4, 256, 0, stream>>>(WS, pool + PO_A3S, pool + PO_A3D, es, ed);
    k_agg<6, 121, true, false, true><<<N_NODES, 256, 0, stream>>>(
        WS, WS + 726, es, ed, rp, ss, pool + PO_B3, pool + PO_BL3, d_out, 121, flags);
}